// Round 4
// baseline (2138.412 us; speedup 1.0000x reference)
//
#include <hip/hip_runtime.h>
#include <hip/hip_bf16.h>
#include <stdint.h>

#define DEV __device__ __forceinline__

// Problem constants
constexpr int B_ = 8, N_ = 131072, S_ = 1024, C_ = 32;
constexpr float INV_R1 = 2.5f;   // 1/RADIUS (0.4)
constexpr float INV_R2 = 1.25f;  // 1/RADIUS_POST (0.8)

// Scaled-weight region offsets (in floats) inside ws
constexpr int OW1AS = 0;        // w1a*s1a      [38][32]
constexpr int OW1BS = 1216;     // w1b*s1b      [32][64]
constexpr int OT1B  = 3264;     // t1b          [64]
constexpr int OW2S  = 3328;     // w2*s2        [70][64]
constexpr int OT2   = 7808;     // t2           [64]
constexpr int OW3AS = 7872;     // w3a*s3a      [64][256]
constexpr int OT3A  = 24256;    // t3a          [256]
constexpr int OW3BS = 24512;    // w3b*s3b     [256][64]
constexpr int OT3B  = 40896;    // t3b          [64]   -> 40960 floats total

// ws byte offsets (layout kept identical to round-0 baseline)
constexpr size_t WS_CTR  = 163840;                          // ctr records [8192][104] f32
constexpr size_t WS_NF   = WS_CTR  + (size_t)8192*104*4;    // new_features [8192][64] f32
constexpr size_t WS_P2   = WS_NF   + (size_t)524288*4;      // stage2 point-precompute [8192][64] f32
constexpr size_t WS_HOUT = WS_P2   + (size_t)524288*4;      // (unused now)
constexpr size_t WS_PREC = WS_HOUT + (size_t)524288*4;      // point records P [B*N][32] bf16

// ---- probe scratch (measurement round only; 512MiB ws, we stay < 350MiB) ----
constexpr size_t MiB = 1048576;
constexpr size_t WS_PP0   = 80*MiB;   // k_points probe dst A (64MiB)
constexpr size_t WS_PP1   = 160*MiB;  // k_points probe dst B (64MiB)
constexpr size_t WS_S1P0  = 300*MiB;  // stage1 probe scratch A (~8MiB)
constexpr size_t WS_S1P1  = 320*MiB;  // stage1 probe scratch B
constexpr size_t WS_S23P0 = 340*MiB;  // stage23 probe out1 scratch A (2MiB)
constexpr size_t WS_S23P1 = 344*MiB;  // stage23 probe out1 scratch B

constexpr int REP_P  = 6;   // k_points probe reps   -> expect 150-450us dispatch
constexpr int REP_S1 = 6;   // stage1 probe reps     -> expect 120-480us
constexpr int REP_S23= 16;  // stage23 probe reps    -> expect 130-900us

DEV float bfu(uint16_t u){ return __uint_as_float(((uint32_t)u) << 16); }

// ---------------------------------------------------------------- k_weights
__global__ void k_weights(
    const float* __restrict__ w1a, const float* __restrict__ s1a,
    const float* __restrict__ w1b, const float* __restrict__ s1b,
    const float* __restrict__ t1b,
    const float* __restrict__ w2,  const float* __restrict__ s2,
    const float* __restrict__ t2,
    const float* __restrict__ w3a, const float* __restrict__ s3a,
    const float* __restrict__ t3a,
    const float* __restrict__ w3b, const float* __restrict__ s3b,
    const float* __restrict__ t3b,
    float* __restrict__ wsw)
{
  int t = blockIdx.x*256 + threadIdx.x;
  int nth = gridDim.x*256;
  for (int i=t;i<38*32;i+=nth)  wsw[OW1AS+i] = w1a[i]*s1a[i&31];
  for (int i=t;i<32*64;i+=nth)  wsw[OW1BS+i] = w1b[i]*s1b[i&63];
  for (int i=t;i<64;i+=nth)     wsw[OT1B+i]  = t1b[i];
  for (int i=t;i<70*64;i+=nth)  wsw[OW2S+i]  = w2[i]*s2[i&63];
  for (int i=t;i<64;i+=nth)     wsw[OT2+i]   = t2[i];
  for (int i=t;i<64*256;i+=nth) wsw[OW3AS+i] = w3a[i]*s3a[i&255];
  for (int i=t;i<256;i+=nth)    wsw[OT3A+i]  = t3a[i];
  for (int i=t;i<256*64;i+=nth) wsw[OW3BS+i] = w3b[i]*s3b[i&63];
  for (int i=t;i<64;i+=nth)     wsw[OT3B+i]  = t3b[i];
}

// ---------------------------------------------------------------- k_points
__global__ __launch_bounds__(256) void k_points(
    const float* __restrict__ locs,
    const float* __restrict__ feats,
    const float* __restrict__ wsw,
    __hip_bfloat16* __restrict__ prec)
{
  size_t p = (size_t)blockIdx.x*256 + threadIdx.x;   // 0 .. B*N-1
  int b = (int)(p >> 17);
  int pinb = (int)(p & (size_t)(N_-1));

  float x = locs[p*3+0]*INV_R1;
  float y = locs[p*3+1]*INV_R1;
  float z = locs[p*3+2]*INV_R1;

  float acc[32];
  #pragma unroll
  for (int j=0;j<32;j++)
    acc[j] = x*wsw[OW1AS+j] + y*wsw[OW1AS+32+j] + z*wsw[OW1AS+64+j];

  const float* fb = feats + (size_t)b*C_*N_ + pinb;
  float fcur[8], fnxt[8];
  #pragma unroll
  for (int i=0;i<8;i++) fcur[i] = fb[(size_t)i*N_];
  #pragma unroll
  for (int ch=0;ch<4;ch++){
    if (ch<3){
      #pragma unroll
      for (int i=0;i<8;i++) fnxt[i] = fb[(size_t)(8*(ch+1)+i)*N_];
    }
    #pragma unroll
    for (int i=0;i<8;i++){
      int c = 8*ch+i;
      #pragma unroll
      for (int j=0;j<32;j++)
        acc[j] = fmaf(fcur[i], wsw[OW1AS + (6+c)*32 + j], acc[j]);
    }
    #pragma unroll
    for (int i=0;i<8;i++) fcur[i] = fnxt[i];
  }
  union U { float4 v[4]; __hip_bfloat16 h[32]; } r;
  #pragma unroll
  for (int j=0;j<32;j++) r.h[j] = __float2bfloat16(acc[j]);
  float4* dst = (float4*)(prec + p*32);
  dst[0]=r.v[0]; dst[1]=r.v[1]; dst[2]=r.v[2]; dst[3]=r.v[3];
}

// ---------------------------------------------------------------- k_stage1c
__global__ __launch_bounds__(256) void k_stage1c(
    const float* __restrict__ locs,
    const float* __restrict__ boxes,
    const int* __restrict__ fps_inds,
    const float* __restrict__ t1a,
    const int* __restrict__ ninds,
    const __hip_bfloat16* __restrict__ prec,
    const float* __restrict__ wsw,
    float* __restrict__ ctr,
    float* __restrict__ nf,
    float* __restrict__ p2,
    float* __restrict__ out0,
    float* __restrict__ out2,
    float* __restrict__ out3)
{
  int wid  = (blockIdx.x*256 + threadIdx.x) >> 6;  // 0..8191 = b*S+s
  int lane = threadIdx.x & 63;
  int uwid = __builtin_amdgcn_readfirstlane(wid);
  int b = uwid >> 10;

  int idx = fps_inds[uwid];
  size_t src = (size_t)b*N_ + (uint32_t)idx;
  float cx = locs[src*3+0], cy = locs[src*3+1], cz = locs[src*3+2];
  float bx0=boxes[src*6+0], bx1=boxes[src*6+1], bx2=boxes[src*6+2];
  float bx3=boxes[src*6+3], bx4=boxes[src*6+4], bx5=boxes[src*6+5];
  float d0=bx3-bx0, d1=bx4-bx1, d2=bx5-bx2;

  if (lane==0){
    out0[(size_t)uwid*3+0]=cx; out0[(size_t)uwid*3+1]=cy; out0[(size_t)uwid*3+2]=cz;
    out2[(size_t)uwid*6+0]=bx0; out2[(size_t)uwid*6+1]=bx1; out2[(size_t)uwid*6+2]=bx2;
    out2[(size_t)uwid*6+3]=bx3; out2[(size_t)uwid*6+4]=bx4; out2[(size_t)uwid*6+5]=bx5;
    out3[uwid] = (float)idx;
    ctr[(size_t)uwid*104+3]=d0; ctr[(size_t)uwid*104+4]=d1; ctr[(size_t)uwid*104+5]=d2;
  }
  {
    int j = lane & 31;
    float xr=cx*INV_R1, yr=cy*INV_R1, zr=cz*INV_R1;
    float c8 = t1a[j] - xr*wsw[OW1AS+j] - yr*wsw[OW1AS+32+j] - zr*wsw[OW1AS+64+j];
    float xq=cx*INV_R2, yq=cy*INV_R2, zq=cz*INV_R2;
    float q2l = wsw[OT2+lane] - xq*wsw[OW2S+lane] - yq*wsw[OW2S+64+lane] - zq*wsw[OW2S+128+lane];
    ctr[(size_t)uwid*104+40+lane] = q2l;

    int nbr = ninds[(size_t)uwid*64 + lane];
    size_t gp = (size_t)b*N_ + (uint32_t)nbr;

    union U { float4 v[4]; uint16_t u[32]; } r;
    const float4* psrc = (const float4*)(prec + gp*32);
    r.v[0]=psrc[0]; r.v[1]=psrc[1]; r.v[2]=psrc[2]; r.v[3]=psrc[3];

    const float2* bp = (const float2*)(boxes + gp*6);
    float2 q0=bp[0], q1=bp[1], q2=bp[2];

    float ad0=fabsf((q1.y-q0.x)-d0);
    float ad1=fabsf((q2.x-q0.y)-d1);
    float ad2=fabsf((q2.y-q1.x)-d2);

    float h[32];
    #pragma unroll
    for (int i=0;i<32;i++){
      float p = bfu(r.u[i]);
      float v = p + __shfl(c8, i) + ad0*wsw[OW1AS+96+i] + ad1*wsw[OW1AS+128+i] + ad2*wsw[OW1AS+160+i];
      h[i] = fmaxf(v, 0.f);
    }
    float acc[64];
    #pragma unroll
    for (int j2=0;j2<64;j2++) acc[j2] = wsw[OT1B+j2];
    #pragma unroll
    for (int i=0;i<32;i++){
      #pragma unroll
      for (int j2=0;j2<64;j2++)
        acc[j2] = fmaf(h[i], wsw[OW1BS + i*64 + j2], acc[j2]);
    }
    #pragma unroll
    for (int s=32;s>=1;s>>=1){
      bool up = (lane & s) != 0;
      #pragma unroll
      for (int i=0;i<s;i++){
        float lo = fmaxf(acc[i],   __shfl_xor(acc[i],   s));
        float hi = fmaxf(acc[s+i], __shfl_xor(acc[s+i], s));
        acc[i] = up ? hi : lo;
      }
    }
    float mine = fmaxf(acc[0], 0.f);
    nf[(size_t)uwid*64 + lane] = mine;

    float pv = (cx*INV_R2)*wsw[OW2S+lane]
             + (cy*INV_R2)*wsw[OW2S+64+lane]
             + (cz*INV_R2)*wsw[OW2S+128+lane];
    #pragma unroll
    for (int i=0;i<64;i++)
      pv = fmaf(__shfl(mine, i), wsw[OW2S + (6+i)*64 + lane], pv);
    p2[(size_t)uwid*64 + lane] = pv;
  }
}

// ---------------------------------------------------------------- k_stage23t
__global__ __launch_bounds__(256) void k_stage23t(
    const int* __restrict__ ninds2,
    const float* __restrict__ wsw,
    const float* __restrict__ ctr,
    const float* __restrict__ nf,
    const float* __restrict__ p2,
    float* __restrict__ out1)
{
  int wid  = (blockIdx.x*256 + threadIdx.x) >> 6;   // 0..2047
  int lane = threadIdx.x & 63;
  int uw = __builtin_amdgcn_readfirstlane(wid);
  int c0 = uw*4;
  int bS = c0 & ~1023;

  float q2v[4], m[4], cd0[4], cd1[4], cd2[4];
  #pragma unroll
  for (int g=0;g<4;g++){
    const float* cr = ctr + (size_t)(c0+g)*104;
    q2v[g] = cr[40+lane];
    cd0[g]=cr[3]; cd1[g]=cr[4]; cd2[g]=cr[5];
    m[g] = -3.4e38f;
  }
  float w30 = wsw[OW2S+192+lane];
  float w31 = wsw[OW2S+256+lane];
  float w32 = wsw[OW2S+320+lane];

  #pragma unroll 4
  for (int k=0;k<64;k++){
    #pragma unroll
    for (int g=0;g<4;g++){
      int nb = ninds2[(size_t)(c0+g)*64 + k];
      int gg = bS + nb;
      const float* ncr = ctr + (size_t)gg*104;
      float a0 = fabsf(ncr[3]-cd0[g]);
      float a1 = fabsf(ncr[4]-cd1[g]);
      float a2 = fabsf(ncr[5]-cd2[g]);
      float v = p2[(size_t)gg*64 + lane] + q2v[g] + a0*w30 + a1*w31 + a2*w32;
      m[g] = fmaxf(m[g], v);
    }
  }

  float h3[4][4];
  #pragma unroll
  for (int g=0;g<4;g++)
    #pragma unroll
    for (int t=0;t<4;t++) h3[g][t] = wsw[OT3A + t*64 + lane];
  #pragma unroll 8
  for (int i=0;i<64;i++){
    float wv0 = wsw[OW3AS + i*256 +   0 + lane];
    float wv1 = wsw[OW3AS + i*256 +  64 + lane];
    float wv2 = wsw[OW3AS + i*256 + 128 + lane];
    float wv3 = wsw[OW3AS + i*256 + 192 + lane];
    #pragma unroll
    for (int g=0;g<4;g++){
      float h2i = __shfl(m[g], i);
      h3[g][0] = fmaf(h2i, wv0, h3[g][0]);
      h3[g][1] = fmaf(h2i, wv1, h3[g][1]);
      h3[g][2] = fmaf(h2i, wv2, h3[g][2]);
      h3[g][3] = fmaf(h2i, wv3, h3[g][3]);
    }
  }
  #pragma unroll
  for (int g=0;g<4;g++)
    #pragma unroll
    for (int t=0;t<4;t++) h3[g][t] = fmaxf(h3[g][t], 0.f);

  float o[4];
  #pragma unroll
  for (int g=0;g<4;g++) o[g] = wsw[OT3B + lane];
  #pragma unroll
  for (int t=0;t<4;t++){
    #pragma unroll 8
    for (int l=0;l<64;l++){
      float wb = wsw[OW3BS + (t*64+l)*64 + lane];
      #pragma unroll
      for (int g=0;g<4;g++)
        o[g] = fmaf(__shfl(h3[g][t], l), wb, o[g]);
    }
  }
  float4 vals;
  float* vp = &vals.x;
  #pragma unroll
  for (int g=0;g<4;g++){
    float idv = nf[(size_t)(c0+g)*64 + lane];
    vp[g] = fmaxf(o[g] + idv, 0.f);
  }
  int b = c0 >> 10;
  int s = c0 & 1023;
  float4* dst = (float4*)(out1 + ((size_t)b*64 + lane)*S_ + s);
  *dst = vals;
}

// ================================================================ PROBES
// Measurement-only kernels: identical phase bodies looped REP times writing
// to ws scratch. Sized so each probe dispatch > 80us => surfaces in rocprof
// top-5 with full counters (phase time = probe_dur / REP). Real outputs are
// untouched; this round's dur_us is sacrificial.

__global__ __launch_bounds__(256) void k_points_probe(
    const float* __restrict__ locs,
    const float* __restrict__ feats,
    const float* __restrict__ wsw,
    __hip_bfloat16* __restrict__ ps0,
    __hip_bfloat16* __restrict__ ps1,
    int rep)
{
  size_t p = (size_t)blockIdx.x*256 + threadIdx.x;
  int b = (int)(p >> 17);
  int pinb = (int)(p & (size_t)(N_-1));
  for (int rr=0; rr<rep; rr++){
    __hip_bfloat16* prec = (rr & 1) ? ps1 : ps0;
    float x = locs[p*3+0]*INV_R1;
    float y = locs[p*3+1]*INV_R1;
    float z = locs[p*3+2]*INV_R1;
    float acc[32];
    #pragma unroll
    for (int j=0;j<32;j++)
      acc[j] = x*wsw[OW1AS+j] + y*wsw[OW1AS+32+j] + z*wsw[OW1AS+64+j];
    const float* fb = feats + (size_t)b*C_*N_ + pinb;
    float fcur[8], fnxt[8];
    #pragma unroll
    for (int i=0;i<8;i++) fcur[i] = fb[(size_t)i*N_];
    #pragma unroll
    for (int ch=0;ch<4;ch++){
      if (ch<3){
        #pragma unroll
        for (int i=0;i<8;i++) fnxt[i] = fb[(size_t)(8*(ch+1)+i)*N_];
      }
      #pragma unroll
      for (int i=0;i<8;i++){
        int c = 8*ch+i;
        #pragma unroll
        for (int j=0;j<32;j++)
          acc[j] = fmaf(fcur[i], wsw[OW1AS + (6+c)*32 + j], acc[j]);
      }
      #pragma unroll
      for (int i=0;i<8;i++) fcur[i] = fnxt[i];
    }
    union U { float4 v[4]; __hip_bfloat16 h[32]; } r;
    #pragma unroll
    for (int j=0;j<32;j++) r.h[j] = __float2bfloat16(acc[j]);
    float4* dst = (float4*)(prec + p*32);
    dst[0]=r.v[0]; dst[1]=r.v[1]; dst[2]=r.v[2]; dst[3]=r.v[3];
  }
}

__global__ __launch_bounds__(256) void k_stage1c_probe(
    const float* __restrict__ locs,
    const float* __restrict__ boxes,
    const int* __restrict__ fps_inds,
    const float* __restrict__ t1a,
    const int* __restrict__ ninds,
    const __hip_bfloat16* __restrict__ prec,
    const float* __restrict__ wsw,
    float* __restrict__ scr0,
    float* __restrict__ scr1,
    int rep)
{
  int wid  = (blockIdx.x*256 + threadIdx.x) >> 6;
  int lane = threadIdx.x & 63;
  int uwid = __builtin_amdgcn_readfirstlane(wid);
  int b = uwid >> 10;
  for (int rr=0; rr<rep; rr++){
    float* scr = (rr & 1) ? scr1 : scr0;
    float* ctr = scr;                         // [8192][104]
    float* nf  = scr + 851968;                // [8192][64]
    float* p2  = nf  + 524288;                // [8192][64]
    float* out0= p2  + 524288;
    float* out2= out0+ 24576;
    float* out3= out2+ 49152;

    int idx = fps_inds[uwid];
    size_t src = (size_t)b*N_ + (uint32_t)idx;
    float cx = locs[src*3+0], cy = locs[src*3+1], cz = locs[src*3+2];
    float bx0=boxes[src*6+0], bx1=boxes[src*6+1], bx2=boxes[src*6+2];
    float bx3=boxes[src*6+3], bx4=boxes[src*6+4], bx5=boxes[src*6+5];
    float d0=bx3-bx0, d1=bx4-bx1, d2=bx5-bx2;

    if (lane==0){
      out0[(size_t)uwid*3+0]=cx; out0[(size_t)uwid*3+1]=cy; out0[(size_t)uwid*3+2]=cz;
      out2[(size_t)uwid*6+0]=bx0; out2[(size_t)uwid*6+1]=bx1; out2[(size_t)uwid*6+2]=bx2;
      out2[(size_t)uwid*6+3]=bx3; out2[(size_t)uwid*6+4]=bx4; out2[(size_t)uwid*6+5]=bx5;
      out3[uwid] = (float)idx;
      ctr[(size_t)uwid*104+3]=d0; ctr[(size_t)uwid*104+4]=d1; ctr[(size_t)uwid*104+5]=d2;
    }
    int j = lane & 31;
    float xr=cx*INV_R1, yr=cy*INV_R1, zr=cz*INV_R1;
    float c8 = t1a[j] - xr*wsw[OW1AS+j] - yr*wsw[OW1AS+32+j] - zr*wsw[OW1AS+64+j];
    float xq=cx*INV_R2, yq=cy*INV_R2, zq=cz*INV_R2;
    float q2l = wsw[OT2+lane] - xq*wsw[OW2S+lane] - yq*wsw[OW2S+64+lane] - zq*wsw[OW2S+128+lane];
    ctr[(size_t)uwid*104+40+lane] = q2l;

    int nbr = ninds[(size_t)uwid*64 + lane];
    size_t gp = (size_t)b*N_ + (uint32_t)nbr;
    union U { float4 v[4]; uint16_t u[32]; } r;
    const float4* psrc = (const float4*)(prec + gp*32);
    r.v[0]=psrc[0]; r.v[1]=psrc[1]; r.v[2]=psrc[2]; r.v[3]=psrc[3];
    const float2* bp = (const float2*)(boxes + gp*6);
    float2 q0=bp[0], q1=bp[1], q2=bp[2];
    float ad0=fabsf((q1.y-q0.x)-d0);
    float ad1=fabsf((q2.x-q0.y)-d1);
    float ad2=fabsf((q2.y-q1.x)-d2);

    float h[32];
    #pragma unroll
    for (int i=0;i<32;i++){
      float p = bfu(r.u[i]);
      float v = p + __shfl(c8, i) + ad0*wsw[OW1AS+96+i] + ad1*wsw[OW1AS+128+i] + ad2*wsw[OW1AS+160+i];
      h[i] = fmaxf(v, 0.f);
    }
    float acc[64];
    #pragma unroll
    for (int j2=0;j2<64;j2++) acc[j2] = wsw[OT1B+j2];
    #pragma unroll
    for (int i=0;i<32;i++){
      #pragma unroll
      for (int j2=0;j2<64;j2++)
        acc[j2] = fmaf(h[i], wsw[OW1BS + i*64 + j2], acc[j2]);
    }
    #pragma unroll
    for (int s=32;s>=1;s>>=1){
      bool up = (lane & s) != 0;
      #pragma unroll
      for (int i=0;i<s;i++){
        float lo = fmaxf(acc[i],   __shfl_xor(acc[i],   s));
        float hi = fmaxf(acc[s+i], __shfl_xor(acc[s+i], s));
        acc[i] = up ? hi : lo;
      }
    }
    float mine = fmaxf(acc[0], 0.f);
    nf[(size_t)uwid*64 + lane] = mine;
    float pv = (cx*INV_R2)*wsw[OW2S+lane]
             + (cy*INV_R2)*wsw[OW2S+64+lane]
             + (cz*INV_R2)*wsw[OW2S+128+lane];
    #pragma unroll
    for (int i=0;i<64;i++)
      pv = fmaf(__shfl(mine, i), wsw[OW2S + (6+i)*64 + lane], pv);
    p2[(size_t)uwid*64 + lane] = pv;
  }
}

__global__ __launch_bounds__(256) void k_stage23t_probe(
    const int* __restrict__ ninds2,
    const float* __restrict__ wsw,
    const float* __restrict__ ctr,
    const float* __restrict__ nf,
    const float* __restrict__ p2,
    float* __restrict__ o1s0,
    float* __restrict__ o1s1,
    int rep)
{
  int wid  = (blockIdx.x*256 + threadIdx.x) >> 6;
  int lane = threadIdx.x & 63;
  int uw = __builtin_amdgcn_readfirstlane(wid);
  int c0 = uw*4;
  int bS = c0 & ~1023;
  for (int rr=0; rr<rep; rr++){
    float* out1 = (rr & 1) ? o1s1 : o1s0;
    float q2v[4], m[4], cd0[4], cd1[4], cd2[4];
    #pragma unroll
    for (int g=0;g<4;g++){
      const float* cr = ctr + (size_t)(c0+g)*104;
      q2v[g] = cr[40+lane];
      cd0[g]=cr[3]; cd1[g]=cr[4]; cd2[g]=cr[5];
      m[g] = -3.4e38f;
    }
    float w30 = wsw[OW2S+192+lane];
    float w31 = wsw[OW2S+256+lane];
    float w32 = wsw[OW2S+320+lane];
    #pragma unroll 4
    for (int k=0;k<64;k++){
      #pragma unroll
      for (int g=0;g<4;g++){
        int nb = ninds2[(size_t)(c0+g)*64 + k];
        int gg = bS + nb;
        const float* ncr = ctr + (size_t)gg*104;
        float a0 = fabsf(ncr[3]-cd0[g]);
        float a1 = fabsf(ncr[4]-cd1[g]);
        float a2 = fabsf(ncr[5]-cd2[g]);
        float v = p2[(size_t)gg*64 + lane] + q2v[g] + a0*w30 + a1*w31 + a2*w32;
        m[g] = fmaxf(m[g], v);
      }
    }
    float h3[4][4];
    #pragma unroll
    for (int g=0;g<4;g++)
      #pragma unroll
      for (int t=0;t<4;t++) h3[g][t] = wsw[OT3A + t*64 + lane];
    #pragma unroll 8
    for (int i=0;i<64;i++){
      float wv0 = wsw[OW3AS + i*256 +   0 + lane];
      float wv1 = wsw[OW3AS + i*256 +  64 + lane];
      float wv2 = wsw[OW3AS + i*256 + 128 + lane];
      float wv3 = wsw[OW3AS + i*256 + 192 + lane];
      #pragma unroll
      for (int g=0;g<4;g++){
        float h2i = __shfl(m[g], i);
        h3[g][0] = fmaf(h2i, wv0, h3[g][0]);
        h3[g][1] = fmaf(h2i, wv1, h3[g][1]);
        h3[g][2] = fmaf(h2i, wv2, h3[g][2]);
        h3[g][3] = fmaf(h2i, wv3, h3[g][3]);
      }
    }
    #pragma unroll
    for (int g=0;g<4;g++)
      #pragma unroll
      for (int t=0;t<4;t++) h3[g][t] = fmaxf(h3[g][t], 0.f);
    float o[4];
    #pragma unroll
    for (int g=0;g<4;g++) o[g] = wsw[OT3B + lane];
    #pragma unroll
    for (int t=0;t<4;t++){
      #pragma unroll 8
      for (int l=0;l<64;l++){
        float wb = wsw[OW3BS + (t*64+l)*64 + lane];
        #pragma unroll
        for (int g=0;g<4;g++)
          o[g] = fmaf(__shfl(h3[g][t], l), wb, o[g]);
      }
    }
    float4 vals;
    float* vp = &vals.x;
    #pragma unroll
    for (int g=0;g<4;g++){
      float idv = nf[(size_t)(c0+g)*64 + lane];
      vp[g] = fmaxf(o[g] + idv, 0.f);
    }
    int b = c0 >> 10;
    int s = c0 & 1023;
    float4* dst = (float4*)(out1 + ((size_t)b*64 + lane)*S_ + s);
    *dst = vals;
  }
}

// ---------------------------------------------------------------- launch
extern "C" void kernel_launch(void* const* d_in, const int* in_sizes, int n_in,
                              void* d_out, int out_size, void* d_ws, size_t ws_size,
                              hipStream_t stream) {
  const float* locs  = (const float*)d_in[0];
  const float* feats = (const float*)d_in[1];
  const float* boxes = (const float*)d_in[2];
  const int* fps_inds = (const int*)d_in[3];
  const int* ninds    = (const int*)d_in[4];
  const int* ninds2   = (const int*)d_in[5];
  const float* w1a=(const float*)d_in[6];
  const float* s1a=(const float*)d_in[7];
  const float* t1a=(const float*)d_in[8];
  const float* w1b=(const float*)d_in[9];
  const float* s1b=(const float*)d_in[10];
  const float* t1b=(const float*)d_in[11];
  const float* w2 =(const float*)d_in[12];
  const float* s2 =(const float*)d_in[13];
  const float* t2 =(const float*)d_in[14];
  const float* w3a=(const float*)d_in[15];
  const float* s3a=(const float*)d_in[16];
  const float* t3a=(const float*)d_in[17];
  const float* w3b=(const float*)d_in[18];
  const float* s3b=(const float*)d_in[19];
  const float* t3b=(const float*)d_in[20];

  float* wsw  = (float*)d_ws;
  float* ctr  = (float*)((char*)d_ws + WS_CTR);
  float* nf   = (float*)((char*)d_ws + WS_NF);
  float* p2b  = (float*)((char*)d_ws + WS_P2);
  __hip_bfloat16* prec = (__hip_bfloat16*)((char*)d_ws + WS_PREC);

  float* out  = (float*)d_out;
  float* out0 = out;              // fps_locs  [B,S,3]
  float* out1 = out + 24576;      // features  [B,64,S]
  float* out2 = out + 548864;     // fps_boxes [B,S,6]
  float* out3 = out + 598016;     // fps_inds  [B,S]

  // ---- real pipeline (identical to round 3, measured 398us) ----
  k_weights<<<160, 256, 0, stream>>>(w1a,s1a,w1b,s1b,t1b,w2,s2,t2,w3a,s3a,t3a,w3b,s3b,t3b,wsw);
  k_points<<<4096, 256, 0, stream>>>(locs, feats, wsw, prec);
  k_stage1c<<<2048, 256, 0, stream>>>(locs, boxes, fps_inds, t1a, ninds, prec, wsw, ctr, nf, p2b, out0, out2, out3);
  k_stage23t<<<512, 256, 0, stream>>>(ninds2, wsw, ctr, nf, p2b, out1);

  // ---- probes (scratch only; surfaces per-phase counters in rocprof top-5) ----
  __hip_bfloat16* pp0 = (__hip_bfloat16*)((char*)d_ws + WS_PP0);
  __hip_bfloat16* pp1 = (__hip_bfloat16*)((char*)d_ws + WS_PP1);
  float* s1p0 = (float*)((char*)d_ws + WS_S1P0);
  float* s1p1 = (float*)((char*)d_ws + WS_S1P1);
  float* s23p0 = (float*)((char*)d_ws + WS_S23P0);
  float* s23p1 = (float*)((char*)d_ws + WS_S23P1);

  k_points_probe<<<4096, 256, 0, stream>>>(locs, feats, wsw, pp0, pp1, REP_P);
  k_stage1c_probe<<<2048, 256, 0, stream>>>(locs, boxes, fps_inds, t1a, ninds, prec, wsw, s1p0, s1p1, REP_S1);
  k_stage23t_probe<<<512, 256, 0, stream>>>(ninds2, wsw, ctr, nf, p2b, s23p0, s23p1, REP_S23);
}

// Round 6
// 379.737 us; speedup vs baseline: 5.6313x; 5.6313x over previous
//
#include <hip/hip_runtime.h>
#include <hip/hip_bf16.h>
#include <stdint.h>

#define DEV __device__ __forceinline__

// Problem constants
constexpr int B_ = 8, N_ = 131072, S_ = 1024, C_ = 32;
constexpr float INV_R1 = 2.5f;   // 1/RADIUS (0.4)
constexpr float INV_R2 = 1.25f;  // 1/RADIUS_POST (0.8)

// Scaled-weight region offsets (in floats) inside ws
constexpr int OW1AS = 0;        // w1a*s1a      [38][32]
constexpr int OW1BS = 1216;     // w1b*s1b      [32][64]
constexpr int OT1B  = 3264;     // t1b          [64]
constexpr int OW2S  = 3328;     // w2*s2        [70][64]
constexpr int OT2   = 7808;     // t2           [64]
constexpr int OW3AS = 7872;     // w3a*s3a      [64][256]
constexpr int OT3A  = 24256;    // t3a          [256]
constexpr int OW3BS = 24512;    // w3b*s3b     [256][64]
constexpr int OT3B  = 40896;    // t3b          [64]   -> 40960 floats total

// ws byte offsets
constexpr size_t WS_CTR  = 163840;                          // ctr records [8192][104] f32
constexpr size_t WS_NF   = WS_CTR  + (size_t)8192*104*4;    // new_features [8192][64] f32
constexpr size_t WS_P2   = WS_NF   + (size_t)524288*4;      // stage2 point-precompute [8192][64] f32
constexpr size_t WS_HOUT = WS_P2   + (size_t)524288*4;      // (unused)
constexpr size_t WS_PREC = WS_HOUT + (size_t)524288*4;      // point records P [B*N][32] bf16
constexpr size_t MiB = 1048576;
constexpr size_t WS_BFRAG = 80*MiB;   // packed W1b B-fragments [4][64][8] bf16 (4KB)

DEV float bfu(uint16_t u){ return __uint_as_float(((uint32_t)u) << 16); }

typedef __attribute__((ext_vector_type(8))) short short8v;   // 8 bf16 = 4 VGPR
typedef __attribute__((ext_vector_type(4))) float float4v;   // mfma C/D

// ---------------------------------------------------------------- k_weights
__global__ void k_weights(
    const float* __restrict__ w1a, const float* __restrict__ s1a,
    const float* __restrict__ w1b, const float* __restrict__ s1b,
    const float* __restrict__ t1b,
    const float* __restrict__ w2,  const float* __restrict__ s2,
    const float* __restrict__ t2,
    const float* __restrict__ w3a, const float* __restrict__ s3a,
    const float* __restrict__ t3a,
    const float* __restrict__ w3b, const float* __restrict__ s3b,
    const float* __restrict__ t3b,
    float* __restrict__ wsw,
    uint16_t* __restrict__ bfrag)
{
  int t = blockIdx.x*256 + threadIdx.x;
  int nth = gridDim.x*256;
  for (int i=t;i<38*32;i+=nth)  wsw[OW1AS+i] = w1a[i]*s1a[i&31];
  for (int i=t;i<32*64;i+=nth)  wsw[OW1BS+i] = w1b[i]*s1b[i&63];
  for (int i=t;i<64;i+=nth)     wsw[OT1B+i]  = t1b[i];
  for (int i=t;i<70*64;i+=nth)  wsw[OW2S+i]  = w2[i]*s2[i&63];
  for (int i=t;i<64;i+=nth)     wsw[OT2+i]   = t2[i];
  for (int i=t;i<64*256;i+=nth) wsw[OW3AS+i] = w3a[i]*s3a[i&255];
  for (int i=t;i<256;i+=nth)    wsw[OT3A+i]  = t3a[i];
  for (int i=t;i<256*64;i+=nth) wsw[OW3BS+i] = w3b[i]*s3b[i&63];
  for (int i=t;i<64;i+=nth)     wsw[OT3B+i]  = t3b[i];
  // B-fragment pack for mfma_f32_16x16x32_bf16: lane l supplies
  // B[k=(l>>4)*8+j][col=l&15] of tile ct (cols 16ct..16ct+15), j=0..7.
  for (int i=t;i<4*64*8;i+=nth){
    int j = i & 7, l = (i>>3) & 63, ct = i >> 9;
    int k = (l>>4)*8 + j;
    int c = ct*16 + (l & 15);
    __hip_bfloat16 v = __float2bfloat16(w1b[k*64 + c] * s1b[c]);
    bfrag[i] = reinterpret_cast<uint16_t&>(v);
  }
}

// ---------------------------------------------------------------- k_points
__global__ __launch_bounds__(256) void k_points(
    const float* __restrict__ locs,
    const float* __restrict__ feats,
    const float* __restrict__ wsw,
    __hip_bfloat16* __restrict__ prec)
{
  size_t p = (size_t)blockIdx.x*256 + threadIdx.x;   // 0 .. B*N-1
  int b = (int)(p >> 17);
  int pinb = (int)(p & (size_t)(N_-1));

  float x = locs[p*3+0]*INV_R1;
  float y = locs[p*3+1]*INV_R1;
  float z = locs[p*3+2]*INV_R1;

  float acc[32];
  #pragma unroll
  for (int j=0;j<32;j++)
    acc[j] = x*wsw[OW1AS+j] + y*wsw[OW1AS+32+j] + z*wsw[OW1AS+64+j];

  const float* fb = feats + (size_t)b*C_*N_ + pinb;
  float fcur[8], fnxt[8];
  #pragma unroll
  for (int i=0;i<8;i++) fcur[i] = fb[(size_t)i*N_];
  #pragma unroll
  for (int ch=0;ch<4;ch++){
    if (ch<3){
      #pragma unroll
      for (int i=0;i<8;i++) fnxt[i] = fb[(size_t)(8*(ch+1)+i)*N_];
    }
    #pragma unroll
    for (int i=0;i<8;i++){
      int c = 8*ch+i;
      #pragma unroll
      for (int j=0;j<32;j++)
        acc[j] = fmaf(fcur[i], wsw[OW1AS + (6+c)*32 + j], acc[j]);
    }
    #pragma unroll
    for (int i=0;i<8;i++) fcur[i] = fnxt[i];
  }
  union U { float4 v[4]; __hip_bfloat16 h[32]; } r;
  #pragma unroll
  for (int j=0;j<32;j++) r.h[j] = __float2bfloat16(acc[j]);
  float4* dst = (float4*)(prec + p*32);
  dst[0]=r.v[0]; dst[1]=r.v[1]; dst[2]=r.v[2]; dst[3]=r.v[3];
}

// ---------------------------------------------------------------- k_stage1m
// MFMA rewrite of stage1 (r4 probe: 142us, VALUBusy 51%, Occ 12%, VGPR 176).
// Layer-2 (h[64x32] @ W1b[32x64]) + neighbor-max was 2048 scalar-weight FMAs
// + 126-shfl fold. Now: h -> bf16 -> per-wave LDS tile (alignas(16): DS b128
// ops REQUIRE 16B alignment; uint16_t shared array alone doesn't guarantee it
// -> the one UB edge in r5, hardened) -> 4 A-frags x 4 pre-packed B-frags ->
// 16 mfma_16x16x32_bf16, max over 4 C-regs + 4 A-tiles + 2 shfl_xor.
// C/D: col=lane&15, row=(lane>>4)*4+reg (m89/m91-verified).
__global__ __launch_bounds__(256, 4) void k_stage1m(
    const float* __restrict__ locs,
    const float* __restrict__ boxes,
    const int* __restrict__ fps_inds,
    const float* __restrict__ t1a,
    const int* __restrict__ ninds,
    const __hip_bfloat16* __restrict__ prec,
    const float* __restrict__ wsw,
    const uint16_t* __restrict__ bfrag,
    float* __restrict__ ctr,
    float* __restrict__ nf,
    float* __restrict__ p2,
    float* __restrict__ out0,
    float* __restrict__ out2,
    float* __restrict__ out3)
{
  __shared__ alignas(16) uint16_t hsh[4][64][40];  // 80B row stride, 20KB/block
  int wid  = (blockIdx.x*256 + threadIdx.x) >> 6;  // 0..8191 = b*S+s
  int lane = threadIdx.x & 63;
  int wv   = threadIdx.x >> 6;                     // wave in block
  int uwid = __builtin_amdgcn_readfirstlane(wid);
  int b = uwid >> 10;

  // B-fragments: center-independent, hoisted (16 VGPR)
  short8v bfr[4];
  #pragma unroll
  for (int ct=0; ct<4; ct++)
    bfr[ct] = *(const short8v*)(bfrag + ct*512 + lane*8);

  // ---- center precompute ----
  int idx = fps_inds[uwid];                        // uniform -> s_load
  size_t src = (size_t)b*N_ + (uint32_t)idx;
  float cx = locs[src*3+0], cy = locs[src*3+1], cz = locs[src*3+2];
  float bx0=boxes[src*6+0], bx1=boxes[src*6+1], bx2=boxes[src*6+2];
  float bx3=boxes[src*6+3], bx4=boxes[src*6+4], bx5=boxes[src*6+5];
  float d0=bx3-bx0, d1=bx4-bx1, d2=bx5-bx2;

  if (lane==0){
    out0[(size_t)uwid*3+0]=cx; out0[(size_t)uwid*3+1]=cy; out0[(size_t)uwid*3+2]=cz;
    out2[(size_t)uwid*6+0]=bx0; out2[(size_t)uwid*6+1]=bx1; out2[(size_t)uwid*6+2]=bx2;
    out2[(size_t)uwid*6+3]=bx3; out2[(size_t)uwid*6+4]=bx4; out2[(size_t)uwid*6+5]=bx5;
    out3[uwid] = (float)idx;
    ctr[(size_t)uwid*104+3]=d0; ctr[(size_t)uwid*104+4]=d1; ctr[(size_t)uwid*104+5]=d2;
  }
  int j = lane & 31;
  float xr=cx*INV_R1, yr=cy*INV_R1, zr=cz*INV_R1;
  float c8 = t1a[j] - xr*wsw[OW1AS+j] - yr*wsw[OW1AS+32+j] - zr*wsw[OW1AS+64+j];
  float xq=cx*INV_R2, yq=cy*INV_R2, zq=cz*INV_R2;
  float q2l = wsw[OT2+lane] - xq*wsw[OW2S+lane] - yq*wsw[OW2S+64+lane] - zq*wsw[OW2S+128+lane];
  ctr[(size_t)uwid*104+40+lane] = q2l;

  // ---- layer 1: h[32] per lane (lane = neighbor) ----
  int nbr = ninds[(size_t)uwid*64 + lane];
  size_t gp = (size_t)b*N_ + (uint32_t)nbr;

  union U { float4 v[4]; uint16_t u[32]; } r;
  const float4* psrc = (const float4*)(prec + gp*32);
  r.v[0]=psrc[0]; r.v[1]=psrc[1]; r.v[2]=psrc[2]; r.v[3]=psrc[3];

  const float2* bp = (const float2*)(boxes + gp*6);
  float2 q0=bp[0], q1=bp[1], q2=bp[2];

  float ad0=fabsf((q1.y-q0.x)-d0);
  float ad1=fabsf((q2.x-q0.y)-d1);
  float ad2=fabsf((q2.y-q1.x)-d2);

  union HU { uint16_t u[32]; uint4 q[4]; } hu;
  #pragma unroll
  for (int i=0;i<32;i++){
    float p = bfu(r.u[i]);
    float v = p + __shfl(c8, i) + ad0*wsw[OW1AS+96+i] + ad1*wsw[OW1AS+128+i] + ad2*wsw[OW1AS+160+i];
    __hip_bfloat16 hb = __float2bfloat16(fmaxf(v, 0.f));
    hu.u[i] = reinterpret_cast<uint16_t&>(hb);
  }
  // stage h (bf16) into this wave's LDS tile, row = neighbor = lane
  uint4* wp = (uint4*)&hsh[wv][lane][0];
  wp[0]=hu.q[0]; wp[1]=hu.q[1]; wp[2]=hu.q[2]; wp[3]=hu.q[3];
  __syncthreads();

  // ---- layer 2 via MFMA + neighbor max ----
  // A-frag (16x16x32): lane l holds A[row=l&15][k=(l>>4)*8+j]
  int rbase = lane & 15;
  int koff  = (lane >> 4) * 8;
  short8v a[4];
  #pragma unroll
  for (int at=0; at<4; at++)
    a[at] = *(const short8v*)&hsh[wv][at*16 + rbase][koff];

  float4v zeroc = {0.f, 0.f, 0.f, 0.f};
  float m0, m1, m2, m3;
  #pragma unroll
  for (int ct=0; ct<4; ct++){
    float mm = -3.4e38f;
    #pragma unroll
    for (int at=0; at<4; at++){
      float4v c = __builtin_amdgcn_mfma_f32_16x16x32_bf16(a[at], bfr[ct], zeroc, 0, 0, 0);
      mm = fmaxf(mm, fmaxf(fmaxf(c[0], c[1]), fmaxf(c[2], c[3])));
    }
    mm = fmaxf(mm, __shfl_xor(mm, 16));
    mm = fmaxf(mm, __shfl_xor(mm, 32));
    if (ct==0) m0=mm; else if (ct==1) m1=mm; else if (ct==2) m2=mm; else m3=mm;
  }
  int g = lane >> 4;
  float msel = g==0 ? m0 : (g==1 ? m1 : (g==2 ? m2 : m3));
  float mine = fmaxf(msel + wsw[OT1B + lane], 0.f);   // + t1b; max(x)+t == max(x+t)
  nf[(size_t)uwid*64 + lane] = mine;

  // P2[s][lane] = (cxyz/R2)@W2[0:3] + nf[s]@W2[6:70]
  float pv = (cx*INV_R2)*wsw[OW2S+lane]
           + (cy*INV_R2)*wsw[OW2S+64+lane]
           + (cz*INV_R2)*wsw[OW2S+128+lane];
  #pragma unroll
  for (int i=0;i<64;i++)
    pv = fmaf(__shfl(mine, i), wsw[OW2S + (6+i)*64 + lane], pv);
  p2[(size_t)uwid*64 + lane] = pv;
}

// ---------------------------------------------------------------- k_stage23t
__global__ __launch_bounds__(256) void k_stage23t(
    const int* __restrict__ ninds2,
    const float* __restrict__ wsw,
    const float* __restrict__ ctr,
    const float* __restrict__ nf,
    const float* __restrict__ p2,
    float* __restrict__ out1)
{
  int wid  = (blockIdx.x*256 + threadIdx.x) >> 6;   // 0..2047
  int lane = threadIdx.x & 63;
  int uw = __builtin_amdgcn_readfirstlane(wid);
  int c0 = uw*4;
  int bS = c0 & ~1023;

  float q2v[4], m[4], cd0[4], cd1[4], cd2[4];
  #pragma unroll
  for (int g=0;g<4;g++){
    const float* cr = ctr + (size_t)(c0+g)*104;
    q2v[g] = cr[40+lane];
    cd0[g]=cr[3]; cd1[g]=cr[4]; cd2[g]=cr[5];
    m[g] = -3.4e38f;
  }
  float w30 = wsw[OW2S+192+lane];
  float w31 = wsw[OW2S+256+lane];
  float w32 = wsw[OW2S+320+lane];

  #pragma unroll 4
  for (int k=0;k<64;k++){
    #pragma unroll
    for (int g=0;g<4;g++){
      int nb = ninds2[(size_t)(c0+g)*64 + k];
      int gg = bS + nb;
      const float* ncr = ctr + (size_t)gg*104;
      float a0 = fabsf(ncr[3]-cd0[g]);
      float a1 = fabsf(ncr[4]-cd1[g]);
      float a2 = fabsf(ncr[5]-cd2[g]);
      float v = p2[(size_t)gg*64 + lane] + q2v[g] + a0*w30 + a1*w31 + a2*w32;
      m[g] = fmaxf(m[g], v);
    }
  }

  float h3[4][4];
  #pragma unroll
  for (int g=0;g<4;g++)
    #pragma unroll
    for (int t=0;t<4;t++) h3[g][t] = wsw[OT3A + t*64 + lane];
  #pragma unroll 8
  for (int i=0;i<64;i++){
    float wv0 = wsw[OW3AS + i*256 +   0 + lane];
    float wv1 = wsw[OW3AS + i*256 +  64 + lane];
    float wv2 = wsw[OW3AS + i*256 + 128 + lane];
    float wv3 = wsw[OW3AS + i*256 + 192 + lane];
    #pragma unroll
    for (int g=0;g<4;g++){
      float h2i = __shfl(m[g], i);
      h3[g][0] = fmaf(h2i, wv0, h3[g][0]);
      h3[g][1] = fmaf(h2i, wv1, h3[g][1]);
      h3[g][2] = fmaf(h2i, wv2, h3[g][2]);
      h3[g][3] = fmaf(h2i, wv3, h3[g][3]);
    }
  }
  #pragma unroll
  for (int g=0;g<4;g++)
    #pragma unroll
    for (int t=0;t<4;t++) h3[g][t] = fmaxf(h3[g][t], 0.f);

  float o[4];
  #pragma unroll
  for (int g=0;g<4;g++) o[g] = wsw[OT3B + lane];
  #pragma unroll
  for (int t=0;t<4;t++){
    #pragma unroll 8
    for (int l=0;l<64;l++){
      float wb = wsw[OW3BS + (t*64+l)*64 + lane];
      #pragma unroll
      for (int g=0;g<4;g++)
        o[g] = fmaf(__shfl(h3[g][t], l), wb, o[g]);
    }
  }
  float4 vals;
  float* vp = &vals.x;
  #pragma unroll
  for (int g=0;g<4;g++){
    float idv = nf[(size_t)(c0+g)*64 + lane];
    vp[g] = fmaxf(o[g] + idv, 0.f);
  }
  int b = c0 >> 10;
  int s = c0 & 1023;
  float4* dst = (float4*)(out1 + ((size_t)b*64 + lane)*S_ + s);
  *dst = vals;
}

// ---------------------------------------------------------------- launch
extern "C" void kernel_launch(void* const* d_in, const int* in_sizes, int n_in,
                              void* d_out, int out_size, void* d_ws, size_t ws_size,
                              hipStream_t stream) {
  const float* locs  = (const float*)d_in[0];
  const float* feats = (const float*)d_in[1];
  const float* boxes = (const float*)d_in[2];
  const int* fps_inds = (const int*)d_in[3];
  const int* ninds    = (const int*)d_in[4];
  const int* ninds2   = (const int*)d_in[5];
  const float* w1a=(const float*)d_in[6];
  const float* s1a=(const float*)d_in[7];
  const float* t1a=(const float*)d_in[8];
  const float* w1b=(const float*)d_in[9];
  const float* s1b=(const float*)d_in[10];
  const float* t1b=(const float*)d_in[11];
  const float* w2 =(const float*)d_in[12];
  const float* s2 =(const float*)d_in[13];
  const float* t2 =(const float*)d_in[14];
  const float* w3a=(const float*)d_in[15];
  const float* s3a=(const float*)d_in[16];
  const float* t3a=(const float*)d_in[17];
  const float* w3b=(const float*)d_in[18];
  const float* s3b=(const float*)d_in[19];
  const float* t3b=(const float*)d_in[20];

  float* wsw  = (float*)d_ws;
  float* ctr  = (float*)((char*)d_ws + WS_CTR);
  float* nf   = (float*)((char*)d_ws + WS_NF);
  float* p2b  = (float*)((char*)d_ws + WS_P2);
  __hip_bfloat16* prec = (__hip_bfloat16*)((char*)d_ws + WS_PREC);
  uint16_t* bfrag = (uint16_t*)((char*)d_ws + WS_BFRAG);

  float* out  = (float*)d_out;
  float* out0 = out;              // fps_locs  [B,S,3]
  float* out1 = out + 24576;      // features  [B,64,S]
  float* out2 = out + 548864;     // fps_boxes [B,S,6]
  float* out3 = out + 598016;     // fps_inds  [B,S]

  k_weights<<<160, 256, 0, stream>>>(w1a,s1a,w1b,s1b,t1b,w2,s2,t2,w3a,s3a,t3a,w3b,s3b,t3b,wsw,bfrag);
  k_points<<<4096, 256, 0, stream>>>(locs, feats, wsw, prec);
  k_stage1m<<<2048, 256, 0, stream>>>(locs, boxes, fps_inds, t1a, ninds, prec, wsw, bfrag, ctr, nf, p2b, out0, out2, out3);
  k_stage23t<<<512, 256, 0, stream>>>(ninds2, wsw, ctr, nf, p2b, out1);
}

// Round 7
// 363.636 us; speedup vs baseline: 5.8806x; 1.0443x over previous
//
#include <hip/hip_runtime.h>
#include <hip/hip_bf16.h>
#include <stdint.h>

#define DEV __device__ __forceinline__

// Problem constants
constexpr int B_ = 8, N_ = 131072, S_ = 1024, C_ = 32;
constexpr float INV_R1 = 2.5f;   // 1/RADIUS (0.4)
constexpr float INV_R2 = 1.25f;  // 1/RADIUS_POST (0.8)

// Scaled-weight region offsets (in floats) inside ws
constexpr int OW1AS = 0;        // w1a*s1a      [38][32]
constexpr int OW1BS = 1216;     // w1b*s1b      [32][64]
constexpr int OT1B  = 3264;     // t1b          [64]
constexpr int OW2S  = 3328;     // w2*s2        [70][64]
constexpr int OT2   = 7808;     // t2           [64]
constexpr int OW3AS = 7872;     // w3a*s3a      [64][256]
constexpr int OT3A  = 24256;    // t3a          [256]
constexpr int OW3BS = 24512;    // w3b*s3b     [256][64]
constexpr int OT3B  = 40896;    // t3b          [64]   -> 40960 floats total

// ws byte offsets
constexpr size_t WS_CTR  = 163840;                          // ctr records [8192][104] f32
constexpr size_t WS_NF   = WS_CTR  + (size_t)8192*104*4;    // new_features [8192][64] f32
constexpr size_t WS_P2   = WS_NF   + (size_t)524288*4;      // stage2 point-precompute [8192][64] f32
constexpr size_t WS_HOUT = WS_P2   + (size_t)524288*4;      // (unused)
constexpr size_t WS_PREC = WS_HOUT + (size_t)524288*4;      // point records P [B*N][32] bf16
constexpr size_t MiB = 1048576;
constexpr size_t WS_BFRAG = 80*MiB;   // packed W1b B-fragments [4][64][8] bf16 (4KB)

DEV float bfu(uint16_t u){ return __uint_as_float(((uint32_t)u) << 16); }

typedef __attribute__((ext_vector_type(8))) short short8v;   // 8 bf16 = 4 VGPR
typedef __attribute__((ext_vector_type(4))) float float4v;   // mfma C/D

// ---------------------------------------------------------------- k_weights
__global__ void k_weights(
    const float* __restrict__ w1a, const float* __restrict__ s1a,
    const float* __restrict__ w1b, const float* __restrict__ s1b,
    const float* __restrict__ t1b,
    const float* __restrict__ w2,  const float* __restrict__ s2,
    const float* __restrict__ t2,
    const float* __restrict__ w3a, const float* __restrict__ s3a,
    const float* __restrict__ t3a,
    const float* __restrict__ w3b, const float* __restrict__ s3b,
    const float* __restrict__ t3b,
    float* __restrict__ wsw,
    uint16_t* __restrict__ bfrag)
{
  int t = blockIdx.x*256 + threadIdx.x;
  int nth = gridDim.x*256;
  for (int i=t;i<38*32;i+=nth)  wsw[OW1AS+i] = w1a[i]*s1a[i&31];
  for (int i=t;i<32*64;i+=nth)  wsw[OW1BS+i] = w1b[i]*s1b[i&63];
  for (int i=t;i<64;i+=nth)     wsw[OT1B+i]  = t1b[i];
  for (int i=t;i<70*64;i+=nth)  wsw[OW2S+i]  = w2[i]*s2[i&63];
  for (int i=t;i<64;i+=nth)     wsw[OT2+i]   = t2[i];
  for (int i=t;i<64*256;i+=nth) wsw[OW3AS+i] = w3a[i]*s3a[i&255];
  for (int i=t;i<256;i+=nth)    wsw[OT3A+i]  = t3a[i];
  for (int i=t;i<256*64;i+=nth) wsw[OW3BS+i] = w3b[i]*s3b[i&63];
  for (int i=t;i<64;i+=nth)     wsw[OT3B+i]  = t3b[i];
  // B-fragment pack for mfma_f32_16x16x32_bf16: lane l supplies
  // B[k=(l>>4)*8+j][col=l&15] of tile ct (cols 16ct..16ct+15), j=0..7.
  for (int i=t;i<4*64*8;i+=nth){
    int j = i & 7, l = (i>>3) & 63, ct = i >> 9;
    int k = (l>>4)*8 + j;
    int c = ct*16 + (l & 15);
    __hip_bfloat16 v = __float2bfloat16(w1b[k*64 + c] * s1b[c]);
    bfrag[i] = reinterpret_cast<uint16_t&>(v);
  }
}

// ---------------------------------------------------------------- k_points
// r6 counters: 83us, HBM 21%, VALU 20%, Occ 36%, VGPR 52 => latency-bound
// with only 8 outstanding loads. Fix: issue ALL 32 feats loads upfront
// (f[32], ~85 VGPR) -> 4x memory-level parallelism per thread.
__global__ __launch_bounds__(256) void k_points(
    const float* __restrict__ locs,
    const float* __restrict__ feats,
    const float* __restrict__ wsw,
    __hip_bfloat16* __restrict__ prec)
{
  size_t p = (size_t)blockIdx.x*256 + threadIdx.x;   // 0 .. B*N-1
  int b = (int)(p >> 17);
  int pinb = (int)(p & (size_t)(N_-1));

  const float* fb = feats + (size_t)b*C_*N_ + pinb;
  float f[32];
  #pragma unroll
  for (int i=0;i<32;i++) f[i] = fb[(size_t)i*N_];    // 32 outstanding loads

  float x = locs[p*3+0]*INV_R1;
  float y = locs[p*3+1]*INV_R1;
  float z = locs[p*3+2]*INV_R1;

  float acc[32];
  #pragma unroll
  for (int j=0;j<32;j++)
    acc[j] = x*wsw[OW1AS+j] + y*wsw[OW1AS+32+j] + z*wsw[OW1AS+64+j];

  #pragma unroll
  for (int i=0;i<32;i++){
    #pragma unroll
    for (int j=0;j<32;j++)
      acc[j] = fmaf(f[i], wsw[OW1AS + (6+i)*32 + j], acc[j]);  // s_load weights
  }
  union U { float4 v[4]; __hip_bfloat16 h[32]; } r;
  #pragma unroll
  for (int j=0;j<32;j++) r.h[j] = __float2bfloat16(acc[j]);
  float4* dst = (float4*)(prec + p*32);
  dst[0]=r.v[0]; dst[1]=r.v[1]; dst[2]=r.v[2]; dst[3]=r.v[3];
}

// ---------------------------------------------------------------- k_stage1m
// (unchanged from r6 — verified, absmax 0.0625)
__global__ __launch_bounds__(256, 4) void k_stage1m(
    const float* __restrict__ locs,
    const float* __restrict__ boxes,
    const int* __restrict__ fps_inds,
    const float* __restrict__ t1a,
    const int* __restrict__ ninds,
    const __hip_bfloat16* __restrict__ prec,
    const float* __restrict__ wsw,
    const uint16_t* __restrict__ bfrag,
    float* __restrict__ ctr,
    float* __restrict__ nf,
    float* __restrict__ p2,
    float* __restrict__ out0,
    float* __restrict__ out2,
    float* __restrict__ out3)
{
  __shared__ alignas(16) uint16_t hsh[4][64][40];  // 80B row stride, 20KB/block
  int wid  = (blockIdx.x*256 + threadIdx.x) >> 6;  // 0..8191 = b*S+s
  int lane = threadIdx.x & 63;
  int wv   = threadIdx.x >> 6;                     // wave in block
  int uwid = __builtin_amdgcn_readfirstlane(wid);
  int b = uwid >> 10;

  // B-fragments: center-independent, hoisted (16 VGPR)
  short8v bfr[4];
  #pragma unroll
  for (int ct=0; ct<4; ct++)
    bfr[ct] = *(const short8v*)(bfrag + ct*512 + lane*8);

  // ---- center precompute ----
  int idx = fps_inds[uwid];                        // uniform -> s_load
  size_t src = (size_t)b*N_ + (uint32_t)idx;
  float cx = locs[src*3+0], cy = locs[src*3+1], cz = locs[src*3+2];
  float bx0=boxes[src*6+0], bx1=boxes[src*6+1], bx2=boxes[src*6+2];
  float bx3=boxes[src*6+3], bx4=boxes[src*6+4], bx5=boxes[src*6+5];
  float d0=bx3-bx0, d1=bx4-bx1, d2=bx5-bx2;

  if (lane==0){
    out0[(size_t)uwid*3+0]=cx; out0[(size_t)uwid*3+1]=cy; out0[(size_t)uwid*3+2]=cz;
    out2[(size_t)uwid*6+0]=bx0; out2[(size_t)uwid*6+1]=bx1; out2[(size_t)uwid*6+2]=bx2;
    out2[(size_t)uwid*6+3]=bx3; out2[(size_t)uwid*6+4]=bx4; out2[(size_t)uwid*6+5]=bx5;
    out3[uwid] = (float)idx;
    ctr[(size_t)uwid*104+3]=d0; ctr[(size_t)uwid*104+4]=d1; ctr[(size_t)uwid*104+5]=d2;
  }
  int j = lane & 31;
  float xr=cx*INV_R1, yr=cy*INV_R1, zr=cz*INV_R1;
  float c8 = t1a[j] - xr*wsw[OW1AS+j] - yr*wsw[OW1AS+32+j] - zr*wsw[OW1AS+64+j];
  float xq=cx*INV_R2, yq=cy*INV_R2, zq=cz*INV_R2;
  float q2l = wsw[OT2+lane] - xq*wsw[OW2S+lane] - yq*wsw[OW2S+64+lane] - zq*wsw[OW2S+128+lane];
  ctr[(size_t)uwid*104+40+lane] = q2l;

  // ---- layer 1: h[32] per lane (lane = neighbor) ----
  int nbr = ninds[(size_t)uwid*64 + lane];
  size_t gp = (size_t)b*N_ + (uint32_t)nbr;

  union U { float4 v[4]; uint16_t u[32]; } r;
  const float4* psrc = (const float4*)(prec + gp*32);
  r.v[0]=psrc[0]; r.v[1]=psrc[1]; r.v[2]=psrc[2]; r.v[3]=psrc[3];

  const float2* bp = (const float2*)(boxes + gp*6);
  float2 q0=bp[0], q1=bp[1], q2=bp[2];

  float ad0=fabsf((q1.y-q0.x)-d0);
  float ad1=fabsf((q2.x-q0.y)-d1);
  float ad2=fabsf((q2.y-q1.x)-d2);

  union HU { uint16_t u[32]; uint4 q[4]; } hu;
  #pragma unroll
  for (int i=0;i<32;i++){
    float p = bfu(r.u[i]);
    float v = p + __shfl(c8, i) + ad0*wsw[OW1AS+96+i] + ad1*wsw[OW1AS+128+i] + ad2*wsw[OW1AS+160+i];
    __hip_bfloat16 hb = __float2bfloat16(fmaxf(v, 0.f));
    hu.u[i] = reinterpret_cast<uint16_t&>(hb);
  }
  // stage h (bf16) into this wave's LDS tile, row = neighbor = lane
  uint4* wp = (uint4*)&hsh[wv][lane][0];
  wp[0]=hu.q[0]; wp[1]=hu.q[1]; wp[2]=hu.q[2]; wp[3]=hu.q[3];
  __syncthreads();

  // ---- layer 2 via MFMA + neighbor max ----
  int rbase = lane & 15;
  int koff  = (lane >> 4) * 8;
  short8v a[4];
  #pragma unroll
  for (int at=0; at<4; at++)
    a[at] = *(const short8v*)&hsh[wv][at*16 + rbase][koff];

  float4v zeroc = {0.f, 0.f, 0.f, 0.f};
  float m0, m1, m2, m3;
  #pragma unroll
  for (int ct=0; ct<4; ct++){
    float mm = -3.4e38f;
    #pragma unroll
    for (int at=0; at<4; at++){
      float4v c = __builtin_amdgcn_mfma_f32_16x16x32_bf16(a[at], bfr[ct], zeroc, 0, 0, 0);
      mm = fmaxf(mm, fmaxf(fmaxf(c[0], c[1]), fmaxf(c[2], c[3])));
    }
    mm = fmaxf(mm, __shfl_xor(mm, 16));
    mm = fmaxf(mm, __shfl_xor(mm, 32));
    if (ct==0) m0=mm; else if (ct==1) m1=mm; else if (ct==2) m2=mm; else m3=mm;
  }
  int g = lane >> 4;
  float msel = g==0 ? m0 : (g==1 ? m1 : (g==2 ? m2 : m3));
  float mine = fmaxf(msel + wsw[OT1B + lane], 0.f);   // + t1b; max(x)+t == max(x+t)
  nf[(size_t)uwid*64 + lane] = mine;

  // P2[s][lane] = (cxyz/R2)@W2[0:3] + nf[s]@W2[6:70]
  float pv = (cx*INV_R2)*wsw[OW2S+lane]
           + (cy*INV_R2)*wsw[OW2S+64+lane]
           + (cz*INV_R2)*wsw[OW2S+128+lane];
  #pragma unroll
  for (int i=0;i<64;i++)
    pv = fmaf(__shfl(mine, i), wsw[OW2S + (6+i)*64 + lane], pv);
  p2[(size_t)uwid*64 + lane] = pv;
}

// ---------------------------------------------------------------- k_stage23t
// r4 probe: 33us at 2 waves/SIMD (512 blocks), ~75% stall => latency-bound
// at low occupancy. G=4 -> G=2: 4096 waves (1024 blocks), 2x occupancy;
// unroll 8 keeps per-wave MLP. Weight re-reads stay L2-resident.
__global__ __launch_bounds__(256) void k_stage23t(
    const int* __restrict__ ninds2,
    const float* __restrict__ wsw,
    const float* __restrict__ ctr,
    const float* __restrict__ nf,
    const float* __restrict__ p2,
    float* __restrict__ out1)
{
  int wid  = (blockIdx.x*256 + threadIdx.x) >> 6;   // 0..4095
  int lane = threadIdx.x & 63;
  int uw = __builtin_amdgcn_readfirstlane(wid);
  int c0 = uw*2;                                    // first center (2 | 1024)
  int bS = c0 & ~1023;

  float q2v[2], m[2], cd0[2], cd1[2], cd2[2];
  #pragma unroll
  for (int g=0;g<2;g++){
    const float* cr = ctr + (size_t)(c0+g)*104;
    q2v[g] = cr[40+lane];
    cd0[g]=cr[3]; cd1[g]=cr[4]; cd2[g]=cr[5];
    m[g] = -3.4e38f;
  }
  float w30 = wsw[OW2S+192+lane];
  float w31 = wsw[OW2S+256+lane];
  float w32 = wsw[OW2S+320+lane];

  #pragma unroll 8
  for (int k=0;k<64;k++){
    #pragma unroll
    for (int g=0;g<2;g++){
      int nb = ninds2[(size_t)(c0+g)*64 + k];       // uniform -> s_load
      int gg = bS + nb;
      const float* ncr = ctr + (size_t)gg*104;
      float a0 = fabsf(ncr[3]-cd0[g]);
      float a1 = fabsf(ncr[4]-cd1[g]);
      float a2 = fabsf(ncr[5]-cd2[g]);
      float v = p2[(size_t)gg*64 + lane] + q2v[g] + a0*w30 + a1*w31 + a2*w32;
      m[g] = fmaxf(m[g], v);
    }
  }

  // MLP3 layer 1: h3[g][t] for channel t*64+lane
  float h3[2][4];
  #pragma unroll
  for (int g=0;g<2;g++)
    #pragma unroll
    for (int t=0;t<4;t++) h3[g][t] = wsw[OT3A + t*64 + lane];
  #pragma unroll 8
  for (int i=0;i<64;i++){
    float wv0 = wsw[OW3AS + i*256 +   0 + lane];
    float wv1 = wsw[OW3AS + i*256 +  64 + lane];
    float wv2 = wsw[OW3AS + i*256 + 128 + lane];
    float wv3 = wsw[OW3AS + i*256 + 192 + lane];
    #pragma unroll
    for (int g=0;g<2;g++){
      float h2i = __shfl(m[g], i);
      h3[g][0] = fmaf(h2i, wv0, h3[g][0]);
      h3[g][1] = fmaf(h2i, wv1, h3[g][1]);
      h3[g][2] = fmaf(h2i, wv2, h3[g][2]);
      h3[g][3] = fmaf(h2i, wv3, h3[g][3]);
    }
  }
  #pragma unroll
  for (int g=0;g<2;g++)
    #pragma unroll
    for (int t=0;t<4;t++) h3[g][t] = fmaxf(h3[g][t], 0.f);

  // layer 2: o[g][lane] = t3b + sum_i relu(h3)[i] * W3b[i][lane]
  float o[2];
  #pragma unroll
  for (int g=0;g<2;g++) o[g] = wsw[OT3B + lane];
  #pragma unroll
  for (int t=0;t<4;t++){
    #pragma unroll 8
    for (int l=0;l<64;l++){
      float wb = wsw[OW3BS + (t*64+l)*64 + lane];
      #pragma unroll
      for (int g=0;g<2;g++)
        o[g] = fmaf(__shfl(h3[g][t], l), wb, o[g]);
    }
  }
  // skip + relu, write out1[b][lane][s..s+1] as one float2 (8B aligned: s even)
  float2 vals;
  float* vp = &vals.x;
  #pragma unroll
  for (int g=0;g<2;g++){
    float idv = nf[(size_t)(c0+g)*64 + lane];
    vp[g] = fmaxf(o[g] + idv, 0.f);
  }
  int b = c0 >> 10;
  int s = c0 & 1023;
  float2* dst = (float2*)(out1 + ((size_t)b*64 + lane)*S_ + s);
  *dst = vals;
}

// ---------------------------------------------------------------- launch
extern "C" void kernel_launch(void* const* d_in, const int* in_sizes, int n_in,
                              void* d_out, int out_size, void* d_ws, size_t ws_size,
                              hipStream_t stream) {
  const float* locs  = (const float*)d_in[0];
  const float* feats = (const float*)d_in[1];
  const float* boxes = (const float*)d_in[2];
  const int* fps_inds = (const int*)d_in[3];
  const int* ninds    = (const int*)d_in[4];
  const int* ninds2   = (const int*)d_in[5];
  const float* w1a=(const float*)d_in[6];
  const float* s1a=(const float*)d_in[7];
  const float* t1a=(const float*)d_in[8];
  const float* w1b=(const float*)d_in[9];
  const float* s1b=(const float*)d_in[10];
  const float* t1b=(const float*)d_in[11];
  const float* w2 =(const float*)d_in[12];
  const float* s2 =(const float*)d_in[13];
  const float* t2 =(const float*)d_in[14];
  const float* w3a=(const float*)d_in[15];
  const float* s3a=(const float*)d_in[16];
  const float* t3a=(const float*)d_in[17];
  const float* w3b=(const float*)d_in[18];
  const float* s3b=(const float*)d_in[19];
  const float* t3b=(const float*)d_in[20];

  float* wsw  = (float*)d_ws;
  float* ctr  = (float*)((char*)d_ws + WS_CTR);
  float* nf   = (float*)((char*)d_ws + WS_NF);
  float* p2b  = (float*)((char*)d_ws + WS_P2);
  __hip_bfloat16* prec = (__hip_bfloat16*)((char*)d_ws + WS_PREC);
  uint16_t* bfrag = (uint16_t*)((char*)d_ws + WS_BFRAG);

  float* out  = (float*)d_out;
  float* out0 = out;              // fps_locs  [B,S,3]
  float* out1 = out + 24576;      // features  [B,64,S]
  float* out2 = out + 548864;     // fps_boxes [B,S,6]
  float* out3 = out + 598016;     // fps_inds  [B,S]

  k_weights<<<160, 256, 0, stream>>>(w1a,s1a,w1b,s1b,t1b,w2,s2,t2,w3a,s3a,t3a,w3b,s3b,t3b,wsw,bfrag);
  k_points<<<4096, 256, 0, stream>>>(locs, feats, wsw, prec);
  k_stage1m<<<2048, 256, 0, stream>>>(locs, boxes, fps_inds, t1a, ninds, prec, wsw, bfrag, ctr, nf, p2b, out0, out2, out3);
  k_stage23t<<<1024, 256, 0, stream>>>(ninds2, wsw, ctr, nf, p2b, out1);
}